// Round 5
// baseline (704.367 us; speedup 1.0000x reference)
//
#include <hip/hip_runtime.h>

// LIF neuron: v_t = ALPHA*v_{t-1} + (x_t . w) - V_TH*z_{t-1}; z_t = 1[v_t > V_TH]
// x: [B=128, T=1000, N=1024] fp32, w: [N] fp32.
// Out: v_seq [B,T] ++ z_seq [B,T], flat fp32.
//
// NOTE: dur_us includes the harness's per-iteration restore (~490-520 us:
// 2 GB ws poison @ ~325 us + d_in restore). Kernel floor is x-read
// 524 MB / 6.3 TB/s ~= 83 us + ~12 us scan/gaps.
//
// R6 (probe, single variable vs R5): drop __builtin_nontemporal_load on the
// x reads. Budget arithmetic says the dot runs at ~3.5-4 TB/s effective
// (kernel-side ~150-180 us vs ~95 us floor) while the harness fills hit
// 6.4-6.6 TB/s on the same memory. VALU/TLP margins are ~4-7x, so the
// remaining suspect is the NT (evict-first/L2-bypass) read policy. x is
// streamed exactly once and nothing else needs L2 -> plain loads risk ~0.
//   outcome (a) dur -15..-35 us: NT was throttling; keep tuning dot.
//   outcome (b) dur +-8 us: dot at achieved-BW ceiling -> declare roofline.
// (R7 note: previous submission of this exact source hit an infra failure
// "MI355X container failed twice" -- resubmitting unchanged.)

#define ALPHA 0.995f
#define V_TH 2.0f

constexpr int B = 128;
constexpr int T = 1000;
constexpr int N = 1024;
constexpr int TILE_T = 40;             // scan tile (25 tiles exactly)

typedef float f32x4 __attribute__((ext_vector_type(4)));

// ---------------------------------------------------------------------------
// Kernel 1 (R2/R5 structure, loads now cached): drive_t[t*B+b] = dot(x[row],w),
// row = b*T + t. 8000 blocks x 4 waves; each wave owns 4 rows as a 2-row
// software pipeline (8 KB of loads in flight, 8 independent 4-deep fp64
// chains, two interleaved shuffle-reduce chains). 32000 waves queued deep.
// ---------------------------------------------------------------------------
__global__ __launch_bounds__(256) void lif_dot_kernel(
    const float* __restrict__ x, const float* __restrict__ w,
    float* __restrict__ drive_t) {
    const int lane = threadIdx.x & 63;
    const int gwave = blockIdx.x * 4 + (threadIdx.x >> 6);  // 0..31999
    const int base_row = gwave * 4;                         // 4 rows/wave

    const float* wp = w + lane * 4;
    const f32x4 w0 = *(const f32x4*)(wp);
    const f32x4 w1 = *(const f32x4*)(wp + 256);
    const f32x4 w2 = *(const f32x4*)(wp + 512);
    const f32x4 w3 = *(const f32x4*)(wp + 768);

#pragma unroll
    for (int i = 0; i < 4; i += 2) {
        const f32x4* xr0 = (const f32x4*)(x + (long long)(base_row + i) * N + lane * 4);
        const f32x4* xr1 = (const f32x4*)((const float*)xr0 + N);
        // issue all 8 loads (8 KB/wave) before any use; PLAIN cached loads
        // (R6 probe: NT policy suspected of capping streaming read BW)
        const f32x4 a0 = xr0[0];
        const f32x4 a1 = xr0[64];
        const f32x4 a2 = xr0[128];
        const f32x4 a3 = xr0[192];
        const f32x4 b0 = xr1[0];
        const f32x4 b1 = xr1[64];
        const f32x4 b2 = xr1[128];
        const f32x4 b3 = xr1[192];

        // 8 independent 4-deep fp64 chains
        double s0 = (double)a0.x*w0.x + (double)a0.y*w0.y + (double)a0.z*w0.z + (double)a0.w*w0.w;
        double s1 = (double)a1.x*w1.x + (double)a1.y*w1.y + (double)a1.z*w1.z + (double)a1.w*w1.w;
        double s2 = (double)a2.x*w2.x + (double)a2.y*w2.y + (double)a2.z*w2.z + (double)a2.w*w2.w;
        double s3 = (double)a3.x*w3.x + (double)a3.y*w3.y + (double)a3.z*w3.z + (double)a3.w*w3.w;
        double t0 = (double)b0.x*w0.x + (double)b0.y*w0.y + (double)b0.z*w0.z + (double)b0.w*w0.w;
        double t1 = (double)b1.x*w1.x + (double)b1.y*w1.y + (double)b1.z*w1.z + (double)b1.w*w1.w;
        double t2 = (double)b2.x*w2.x + (double)b2.y*w2.y + (double)b2.z*w2.z + (double)b2.w*w2.w;
        double t3 = (double)b3.x*w3.x + (double)b3.y*w3.y + (double)b3.z*w3.z + (double)b3.w*w3.w;
        double accA = (s0 + s1) + (s2 + s3);
        double accB = (t0 + t1) + (t2 + t3);

        // two interleaved butterfly reductions (latencies overlap)
#pragma unroll
        for (int off = 32; off >= 1; off >>= 1) {
            accA += __shfl_down(accA, off);
            accB += __shfl_down(accB, off);
        }

        if (lane == 0) {
            const int row = base_row + i;
            const int b1_ = row / T;
            const int t1_ = row - b1_ * T;
            drive_t[t1_ * B + b1_] = (float)accA;
            const int row2 = row + 1;
            const int b2_ = row2 / T;
            const int t2_ = row2 - b2_ * T;
            drive_t[t2_ * B + b2_] = (float)accB;
        }
    }
}

// ---------------------------------------------------------------------------
// Kernel 2: sequential LIF scan (R5's validated lean consumer).
// 1 block x 128 threads, one thread per batch row. No LDS, no barriers.
// Per 40-step tile: 40 upfront coalesced loads (drive is [T][B] -> each j is
// a contiguous 512 B line across the 128 threads, L2/L3-resident), then the
// serial recurrence with direct aligned f32x4 stores. ~10 us.
// ---------------------------------------------------------------------------
__global__ __launch_bounds__(128) void lif_scan_kernel(
    const float* __restrict__ drive_t, float* __restrict__ out) {
    const int b = threadIdx.x;  // 0..127
    float v = 0.0f, z = 0.0f;
    for (int t0 = 0; t0 < T; t0 += TILE_T) {
        // batch all 40 loads (independent of the recurrence)
        float d[TILE_T];
#pragma unroll
        for (int j = 0; j < TILE_T; ++j)
            d[j] = drive_t[(t0 + j) * B + b];

        float* vout = out + (long long)b * T + t0;
        float* zout = out + (long long)(B + b) * T + t0;
#pragma unroll
        for (int j4 = 0; j4 < TILE_T; j4 += 4) {
            f32x4 vq, zq;
#pragma unroll
            for (int k = 0; k < 4; ++k) {
                v = ALPHA * v + d[j4 + k] - V_TH * z;
                z = (v - V_TH > 0.0f) ? 1.0f : 0.0f;
                vq[k] = v;
                zq[k] = z;
            }
            *(f32x4*)(vout + j4) = vq;
            *(f32x4*)(zout + j4) = zq;
        }
    }
}

extern "C" void kernel_launch(void* const* d_in, const int* in_sizes, int n_in,
                              void* d_out, int out_size, void* d_ws, size_t ws_size,
                              hipStream_t stream) {
    const float* x = (const float*)d_in[0];   // [B,T,N]
    const float* w = (const float*)d_in[1];   // [N]
    float* out = (float*)d_out;               // v[B,T] ++ z[B,T]
    float* drive_t = (float*)d_ws;            // [T,B] scratch, 512 KB

    // 32000 waves x 4 rows = 128000 rows
    lif_dot_kernel<<<8000, 256, 0, stream>>>(x, w, drive_t);
    lif_scan_kernel<<<1, 128, 0, stream>>>(drive_t, out);
}

// Round 6
// 670.586 us; speedup vs baseline: 1.0504x; 1.0504x over previous
//
#include <hip/hip_runtime.h>

// LIF neuron: v_t = ALPHA*v_{t-1} + (x_t . w) - V_TH*z_{t-1}; z_t = 1[v_t > V_TH]
// x: [B=128, T=1000, N=1024] fp32, w: [N] fp32.
// Out: v_seq [B,T] ++ z_seq [B,T], flat fp32.
//
// NOTE: dur_us includes the harness's per-iteration restore (~490-520 us:
// 2 GB ws poison @ ~325 us + d_in restore). Kernel floor is x-read
// 524 MB / 6.3 TB/s ~= 83 us + ~12 us scan/gaps.
//
// R7 (revert to R5 best, A/B completion): R6 dropped NT loads and REGRESSED
// 669.1 -> 704.4 (+35 us). Mechanism: x is a 524 MB single-use stream vs
// 32 MB aggregate L2 -- plain cached loads churn L2 fill/evict with zero
// reuse; NT evict-first avoids the thrash. NT restored here, byte-identical
// to R5. If this reproduces ~669 (NT effect real) OR lands ~700 (delta was
// noise -> everything since R2 is one +-35 us band), the conclusion is the
// same: dot at achieved-BW ceiling, scan at serial-dependence floor ->
// declare roofline with this kernel.

#define ALPHA 0.995f
#define V_TH 2.0f

constexpr int B = 128;
constexpr int T = 1000;
constexpr int N = 1024;
constexpr int TILE_T = 40;             // scan tile (25 tiles exactly)

typedef float f32x4 __attribute__((ext_vector_type(4)));

// ---------------------------------------------------------------------------
// Kernel 1 (R2/R5 proven): drive_t[t*B + b] = dot(x[row,:], w), row = b*T+t.
// 8000 blocks x 4 waves; each wave owns 4 rows, processed as a 2-row
// software pipeline (8 KB of loads in flight, 8 independent 4-deep fp64
// chains, two interleaved shuffle-reduce chains). 32000 waves queued deep
// so the per-row reduce latency hides.
// ---------------------------------------------------------------------------
__global__ __launch_bounds__(256) void lif_dot_kernel(
    const float* __restrict__ x, const float* __restrict__ w,
    float* __restrict__ drive_t) {
    const int lane = threadIdx.x & 63;
    const int gwave = blockIdx.x * 4 + (threadIdx.x >> 6);  // 0..31999
    const int base_row = gwave * 4;                         // 4 rows/wave

    const float* wp = w + lane * 4;
    const f32x4 w0 = *(const f32x4*)(wp);
    const f32x4 w1 = *(const f32x4*)(wp + 256);
    const f32x4 w2 = *(const f32x4*)(wp + 512);
    const f32x4 w3 = *(const f32x4*)(wp + 768);

#pragma unroll
    for (int i = 0; i < 4; i += 2) {
        const f32x4* xr0 = (const f32x4*)(x + (long long)(base_row + i) * N + lane * 4);
        const f32x4* xr1 = (const f32x4*)((const float*)xr0 + N);
        // issue all 8 loads (8 KB/wave) before any use; nontemporal: x is
        // streamed once (524 MB >> 32 MB L2) -- evict-first avoids L2 thrash
        const f32x4 a0 = __builtin_nontemporal_load(xr0);
        const f32x4 a1 = __builtin_nontemporal_load(xr0 + 64);
        const f32x4 a2 = __builtin_nontemporal_load(xr0 + 128);
        const f32x4 a3 = __builtin_nontemporal_load(xr0 + 192);
        const f32x4 b0 = __builtin_nontemporal_load(xr1);
        const f32x4 b1 = __builtin_nontemporal_load(xr1 + 64);
        const f32x4 b2 = __builtin_nontemporal_load(xr1 + 128);
        const f32x4 b3 = __builtin_nontemporal_load(xr1 + 192);

        // 8 independent 4-deep fp64 chains
        double s0 = (double)a0.x*w0.x + (double)a0.y*w0.y + (double)a0.z*w0.z + (double)a0.w*w0.w;
        double s1 = (double)a1.x*w1.x + (double)a1.y*w1.y + (double)a1.z*w1.z + (double)a1.w*w1.w;
        double s2 = (double)a2.x*w2.x + (double)a2.y*w2.y + (double)a2.z*w2.z + (double)a2.w*w2.w;
        double s3 = (double)a3.x*w3.x + (double)a3.y*w3.y + (double)a3.z*w3.z + (double)a3.w*w3.w;
        double t0 = (double)b0.x*w0.x + (double)b0.y*w0.y + (double)b0.z*w0.z + (double)b0.w*w0.w;
        double t1 = (double)b1.x*w1.x + (double)b1.y*w1.y + (double)b1.z*w1.z + (double)b1.w*w1.w;
        double t2 = (double)b2.x*w2.x + (double)b2.y*w2.y + (double)b2.z*w2.z + (double)b2.w*w2.w;
        double t3 = (double)b3.x*w3.x + (double)b3.y*w3.y + (double)b3.z*w3.z + (double)b3.w*w3.w;
        double accA = (s0 + s1) + (s2 + s3);
        double accB = (t0 + t1) + (t2 + t3);

        // two interleaved butterfly reductions (latencies overlap)
#pragma unroll
        for (int off = 32; off >= 1; off >>= 1) {
            accA += __shfl_down(accA, off);
            accB += __shfl_down(accB, off);
        }

        if (lane == 0) {
            const int row = base_row + i;
            const int b1_ = row / T;
            const int t1_ = row - b1_ * T;
            drive_t[t1_ * B + b1_] = (float)accA;
            const int row2 = row + 1;
            const int b2_ = row2 / T;
            const int t2_ = row2 - b2_ * T;
            drive_t[t2_ * B + b2_] = (float)accB;
        }
    }
}

// ---------------------------------------------------------------------------
// Kernel 2: sequential LIF scan (R5's validated lean consumer).
// 1 block x 128 threads, one thread per batch row. No LDS, no barriers.
// Per 40-step tile: 40 upfront coalesced loads (drive is [T][B] -> each j is
// a contiguous 512 B line across the 128 threads, L2/L3-resident), then the
// serial recurrence with direct aligned f32x4 stores. ~10 us.
// ---------------------------------------------------------------------------
__global__ __launch_bounds__(128) void lif_scan_kernel(
    const float* __restrict__ drive_t, float* __restrict__ out) {
    const int b = threadIdx.x;  // 0..127
    float v = 0.0f, z = 0.0f;
    for (int t0 = 0; t0 < T; t0 += TILE_T) {
        // batch all 40 loads (independent of the recurrence)
        float d[TILE_T];
#pragma unroll
        for (int j = 0; j < TILE_T; ++j)
            d[j] = drive_t[(t0 + j) * B + b];

        float* vout = out + (long long)b * T + t0;
        float* zout = out + (long long)(B + b) * T + t0;
#pragma unroll
        for (int j4 = 0; j4 < TILE_T; j4 += 4) {
            f32x4 vq, zq;
#pragma unroll
            for (int k = 0; k < 4; ++k) {
                v = ALPHA * v + d[j4 + k] - V_TH * z;
                z = (v - V_TH > 0.0f) ? 1.0f : 0.0f;
                vq[k] = v;
                zq[k] = z;
            }
            *(f32x4*)(vout + j4) = vq;
            *(f32x4*)(zout + j4) = zq;
        }
    }
}

extern "C" void kernel_launch(void* const* d_in, const int* in_sizes, int n_in,
                              void* d_out, int out_size, void* d_ws, size_t ws_size,
                              hipStream_t stream) {
    const float* x = (const float*)d_in[0];   // [B,T,N]
    const float* w = (const float*)d_in[1];   // [N]
    float* out = (float*)d_out;               // v[B,T] ++ z[B,T]
    float* drive_t = (float*)d_ws;            // [T,B] scratch, 512 KB

    // 32000 waves x 4 rows = 128000 rows
    lif_dot_kernel<<<8000, 256, 0, stream>>>(x, w, drive_t);
    lif_scan_kernel<<<1, 128, 0, stream>>>(drive_t, out);
}